// Round 1
// baseline (532.733 us; speedup 1.0000x reference)
//
#include <hip/hip_runtime.h>
#include <hip/hip_bf16.h>

#define NUSERS 60000
#define NNODES 100000
#define DD 64
#define NGB 1563  // ceil(NNODES/64) — 64-row tiles
#define GMM 782   // k_mm4 grid: exactly 2 tiles per block (balanced)
#define NBUK 196  // ceil(NNODES/512) coarse buckets (dst>>9)
#define ESB 2048  // edges per k_bscatter block
#define ACB 2048  // k_accum blocks (8/CU), grid-stride over nodes
#define DSTR (ACB * 4)  // node stride per wave-stream

typedef __hip_bfloat16 bf16;
using bf16x8 = __attribute__((ext_vector_type(8))) short;
using f32x4  = __attribute__((ext_vector_type(4))) float;

__device__ __forceinline__ float b2f(bf16 x) { return __bfloat162float(x); }
__device__ __forceinline__ bf16 f2b(float x) { return __float2bfloat16(x); }
__device__ __forceinline__ unsigned short fbits(float x) {
    union { bf16 b; unsigned short u; } cv; cv.b = f2b(x); return cv.u;
}
__device__ __forceinline__ float us2f(unsigned short h) {
    union { unsigned u; float f; } t; t.u = (unsigned)h << 16; return t.f;
}
__device__ __forceinline__ float lo_bf16(unsigned w) {
    union { unsigned u; float f; } t; t.u = w << 16; return t.f;
}
__device__ __forceinline__ float hi_bf16(unsigned w) {
    union { unsigned u; float f; } t; t.u = w & 0xFFFF0000u; return t.f;
}
__device__ __forceinline__ float ldf(const void* p, size_t i, int isbf) {
    if (isbf) return b2f(((const bf16*)p)[i]);
    return ((const float*)p)[i];
}
__device__ __forceinline__ unsigned pack2(float a, float b) {
    return (unsigned)fbits(a) | ((unsigned)fbits(b) << 16);
}
__device__ __forceinline__ unsigned pr2(float x0, float x1, float a0, float a1,
                                        float b0, float b1) {
    float t0 = a0 * x0 + b0, t1 = a1 * x1 + b1;
    t0 = t0 > 0.f ? t0 : 0.f;
    t1 = t1 > 0.f ? t1 : 0.f;
    return pack2(t0, t1);
}

// Sniff dtype of u_features (bf16 vs fp32) + zero red[0:256] and btot[0:256].
__global__ void k_sniff(const unsigned short* __restrict__ h,
                        int* __restrict__ flag, float* __restrict__ red,
                        int* __restrict__ btot)
{
    __shared__ int cs[256];
    int t = threadIdx.x;
    int cnt = 0;
    for (int i = t; i < 1024; i += 256) {
        int e = (h[2 * i] >> 7) & 0xFF;
        cnt += (e >= 100 && e <= 140) ? 1 : 0;
    }
    cs[t] = cnt;
    __syncthreads();
    for (int s = 128; s > 0; s >>= 1) {
        if (t < s) cs[t] += cs[t + s];
        __syncthreads();
    }
    if (t == 0) flag[0] = (cs[0] > 512) ? 1 : 0;
    red[t] = 0.f;
    btot[t] = 0;
}

// ---- Bucketed CSR build (dst-sorted edges), once per launch ----
__global__ __launch_bounds__(256) void k_bhist(const int* __restrict__ ee,
                                               int* __restrict__ btot, int E)
{
    __shared__ int h[256];
    int t = threadIdx.x;
    h[t] = 0;
    __syncthreads();
    for (int e = blockIdx.x * 256 + t; e < E; e += gridDim.x * 256)
        atomicAdd(&h[ee[e] >> 9], 1);
    __syncthreads();
    if (h[t]) atomicAdd(&btot[t], h[t]);
}

// NOTE: no bbase[256] — a [256] write would alias bcursor[0] (round-9 fault).
__global__ void k_bscan(const int* __restrict__ btot, int* __restrict__ bbase,
                        int* __restrict__ bcursor)
{
    __shared__ int sd[256];
    int t = threadIdx.x;
    int v = btot[t];
    sd[t] = v;
    __syncthreads();
    for (int off = 1; off < 256; off <<= 1) {
        int x = (t >= off) ? sd[t - off] : 0;
        __syncthreads();
        sd[t] += x;
        __syncthreads();
    }
    int excl = sd[t] - v;
    bbase[t] = excl;
    bcursor[t] = excl;
}

// Entry = (dst&511)<<20 | src  (src < 2^17).
__global__ __launch_bounds__(256) void k_bscatter(
    const int* __restrict__ es, const int* __restrict__ ee,
    int* __restrict__ bcursor, unsigned* __restrict__ ebuf, int E)
{
    __shared__ int h[256], gb[256], lr[256];
    int t = threadIdx.x;
    h[t] = 0;
    lr[t] = 0;
    __syncthreads();
    int base = blockIdx.x * ESB;
    unsigned ent[8];
    int bk[8];
#pragma unroll
    for (int i = 0; i < 8; i++) {
        int e = base + t + i * 256;
        if (e < E) {
            int s = es[e], d = ee[e];
            bk[i] = d >> 9;
            ent[i] = (unsigned)s | ((unsigned)(d & 511) << 20);
            atomicAdd(&h[bk[i]], 1);
        } else bk[i] = -1;
    }
    __syncthreads();
    if (h[t]) gb[t] = atomicAdd(&bcursor[t], h[t]);
    __syncthreads();
#pragma unroll
    for (int i = 0; i < 8; i++) {
        if (bk[i] >= 0) {
            int r = atomicAdd(&lr[bk[i]], 1);
            ebuf[gb[bk[i]] + r] = ent[i];
        }
    }
}

__global__ __launch_bounds__(256) void k_group(
    const int* __restrict__ bbase, const unsigned* __restrict__ ebuf,
    int* __restrict__ rowptr, int* __restrict__ srcidx)
{
    __shared__ int h[512], sc[512];
    int b = blockIdx.x, t = threadIdx.x;
    int lo = bbase[b], hi = bbase[b + 1];
    h[t] = 0;
    h[t + 256] = 0;
    __syncthreads();
    for (int i = lo + t; i < hi; i += 256)
        atomicAdd(&h[ebuf[i] >> 20], 1);
    __syncthreads();
    sc[t] = h[t];
    sc[t + 256] = h[t + 256];
    __syncthreads();
    for (int off = 1; off < 512; off <<= 1) {
        int v0 = (t >= off) ? sc[t - off] : 0;
        int v1 = (t + 256 >= off) ? sc[t + 256 - off] : 0;
        __syncthreads();
        sc[t] += v0;
        sc[t + 256] += v1;
        __syncthreads();
    }
    int n0 = b * 512 + t, n1 = b * 512 + t + 256;
    int e0 = lo + sc[t] - h[t];
    int e1 = lo + sc[t + 256] - h[t + 256];
    if (n0 < NNODES) rowptr[n0] = e0;
    if (n1 < NNODES) rowptr[n1] = e1;
    if (b == NBUK - 1 && t == 0) rowptr[NNODES] = hi;
    h[t] = e0;           // repurpose as fill cursors
    h[t + 256] = e1;
    __syncthreads();
    for (int i = lo + t; i < hi; i += 256) {
        unsigned en = ebuf[i];
        int pos = atomicAdd(&h[en >> 20], 1);
        int s = (int)(en & 0xFFFFF);
        // Pre-multiplied BYTE offset into T (row stride 256 B) — saves
        // per-edge 64-bit address VALU in k_accum.
        srcidx[pos] = (s < NNODES ? s : 0) << 8;
    }
}

// Load one 64-row x tile slice (16 bf16) into registers.
// MODE 0: rows from concat(u,v), dtype per bfflag.
// MODE 1: x = relu(ab*A + ab') with A stored as bf16.
template <int MODE>
__device__ __forceinline__ void stage_load(
    int tile, int tid, int bfflag,
    const void* u, const void* v, const unsigned short* Aacc,
    const float* ab, uint4& w0, uint4& w1)
{
    int r = tid >> 2, c0 = (tid & 3) * 16;
    int row = tile * DD + r;
    int rowc = row < NNODES ? row : NNODES - 1;
    if (MODE == 0) {
        const void* src = (rowc < NUSERS) ? u : v;
        size_t off = (rowc < NUSERS) ? ((size_t)rowc * DD + c0)
                                     : ((size_t)(rowc - NUSERS) * DD + c0);
        if (bfflag) {
            const uint4* p = (const uint4*)((const unsigned short*)src + off);
            w0 = p[0];
            w1 = p[1];
        } else {
            const float4* p = (const float4*)((const float*)src + off);
            float4 f0 = p[0], f1 = p[1], f2 = p[2], f3 = p[3];
            w0 = make_uint4(pack2(f0.x, f0.y), pack2(f0.z, f0.w),
                            pack2(f1.x, f1.y), pack2(f1.z, f1.w));
            w1 = make_uint4(pack2(f2.x, f2.y), pack2(f2.z, f2.w),
                            pack2(f3.x, f3.y), pack2(f3.z, f3.w));
        }
    } else {
        const uint4* p = (const uint4*)(Aacc + (size_t)rowc * DD + c0);
        unsigned aw[8];
        *(uint4*)&aw[0] = p[0];
        *(uint4*)&aw[4] = p[1];
        const float4* pa = (const float4*)(ab + c0);
        const float4* pb = (const float4*)(ab + 64 + c0);
        float av[16], bv[16];
#pragma unroll
        for (int j = 0; j < 4; j++) {
            float4 fa = pa[j], fb = pb[j];
            av[4 * j] = fa.x; av[4 * j + 1] = fa.y;
            av[4 * j + 2] = fa.z; av[4 * j + 3] = fa.w;
            bv[4 * j] = fb.x; bv[4 * j + 1] = fb.y;
            bv[4 * j + 2] = fb.z; bv[4 * j + 3] = fb.w;
        }
        unsigned ow[8];
#pragma unroll
        for (int j = 0; j < 8; j++)
            ow[j] = pr2(lo_bf16(aw[j]), hi_bf16(aw[j]),
                        av[2 * j], av[2 * j + 1], bv[2 * j], bv[2 * j + 1]);
        w0 = *(uint4*)&ow[0];
        w1 = *(uint4*)&ow[4];
    }
}

__device__ __forceinline__ void stage_store(unsigned short* xbuf, int tid,
                                            const uint4& w0, const uint4& w1)
{
    int r = tid >> 2, c0 = (tid & 3) * 16;
    *(uint4*)&xbuf[r * 72 + c0] = w0;
    *((uint4*)&xbuf[r * 72 + c0] + 1) = w1;
}

// ---- MFMA fused 4-GEMM, double-buffered + pipelined. Balanced: 2 tiles/block.
// wave0: A = x@W0 + b0 (bf16 accumulator)
// wave1: Ed = exp(-(x@W1 + b1)) (bf16)  — dst sigmoid factor
// waves 2/3: 2 rowtiles each, BOTH W2,W3:
//            T = bits(x@W2) | bits(exp(-(x@W3)))<<16  (msg | src sigmoid factor)
// MODE 1 additionally computes BN coefficients ab[] in-block from red/gamma/beta
// (fused k_stats — removes a dispatch + dependency hop).
template <int MODE>
__global__ __launch_bounds__(256, 4) void k_mm4_mfma(
    const void* __restrict__ u, const void* __restrict__ v,
    const float* __restrict__ red, const void* __restrict__ gm,
    const void* __restrict__ bt,
    const void* __restrict__ W0, const void* __restrict__ W1,
    const void* __restrict__ W2, const void* __restrict__ W3,
    const void* __restrict__ b0, const void* __restrict__ b1,
    const int* __restrict__ flag,
    unsigned short* __restrict__ A, unsigned short* __restrict__ Ed,
    unsigned* __restrict__ Tw)
{
    __shared__ __align__(16) unsigned short lsd[4 * DD * 72];  // 36,864 B
    __shared__ __align__(16) float abs_s[128];
    const int bfflag = flag[0];
    const int tid = threadIdx.x;

    if (MODE == 1) {
        // fused k_stats: ab = gamma*rstd ; ab' = beta - mean*gamma*rstd
        if (tid < 64) {
            float mean = red[tid] * (1.f / NNODES);
            float var = red[64 + tid] * (1.f / NNODES) - mean * mean;
            float a = ldf(gm, tid, bfflag) * rsqrtf(var + 1e-3f);
            abs_s[tid] = a;
            abs_s[64 + tid] = ldf(bt, tid, bfflag) - mean * a;
        }
        __syncthreads();
    }

    // Issue first x-tile load ASAP (hidden behind weight staging).
    int t = blockIdx.x;
    uint4 xa, xb;
    stage_load<MODE>(t, tid, bfflag, u, v, A, abs_s, xa, xb);

    if (bfflag) {
#define WSTG_BF(m, src)                                                   \
        _Pragma("unroll")                                                 \
        for (int j = 0; j < 2; j++) {                                     \
            int i = tid + j * 256; int e0 = i * 8;                        \
            *(uint4*)&lsd[(m) * 4608 + (e0 >> 6) * 72 + (e0 & 63)] =      \
                ((const uint4*)(src))[i];                                 \
        }
        WSTG_BF(0, W0) WSTG_BF(1, W1) WSTG_BF(2, W2) WSTG_BF(3, W3)
    } else {
#define WSTG_F32(m, src)                                                  \
        _Pragma("unroll")                                                 \
        for (int j = 0; j < 4; j++) {                                     \
            int i = tid + j * 256; int e0 = i * 4;                        \
            float4 f = ((const float4*)(src))[i];                         \
            *(uint2*)&lsd[(m) * 4608 + (e0 >> 6) * 72 + (e0 & 63)] =      \
                make_uint2(pack2(f.x, f.y), pack2(f.z, f.w));             \
        }
        WSTG_F32(0, W0) WSTG_F32(1, W1) WSTG_F32(2, W2) WSTG_F32(3, W3)
    }
    __syncthreads();

    const int wv = tid >> 6, lane = tid & 63;
    const int quad = lane >> 4, ln = lane & 15;
    const int mA = (wv < 2) ? wv : 2;
    bf16x8 bfrA[2][4], bfrB[2][4];
#pragma unroll
    for (int ks = 0; ks < 2; ks++)
#pragma unroll
        for (int nt = 0; nt < 4; nt++)
#pragma unroll
            for (int j = 0; j < 8; j++)
                bfrA[ks][nt][j] = (short)lsd[mA * 4608 +
                    (ks * 32 + quad * 8 + j) * 72 + nt * 16 + ln];
    if (wv >= 2) {
#pragma unroll
        for (int ks = 0; ks < 2; ks++)
#pragma unroll
            for (int nt = 0; nt < 4; nt++)
#pragma unroll
                for (int j = 0; j < 8; j++)
                    bfrB[ks][nt][j] = (short)lsd[3 * 4608 +
                        (ks * 32 + quad * 8 + j) * 72 + nt * 16 + ln];
    }
    float bias[4];
#pragma unroll
    for (int nt = 0; nt < 4; nt++)
        bias[nt] = (wv == 0) ? ldf(b0, nt * 16 + ln, bfflag)
                 : (wv == 1) ? ldf(b1, nt * 16 + ln, bfflag) : 0.f;
    __syncthreads();  // weights fully consumed; region becomes x buffers

    auto compute = [&](const unsigned short* xt, int row0) {
        if (wv < 2) {
#pragma unroll
            for (int rt = 0; rt < 4; rt++) {
                int m = rt * 16 + ln;
                bf16x8 af0 = *(const bf16x8*)&xt[m * 72 + quad * 8];
                bf16x8 af1 = *(const bf16x8*)&xt[m * 72 + 32 + quad * 8];
#pragma unroll
                for (int nt = 0; nt < 4; nt++) {
                    f32x4 c = {0.f, 0.f, 0.f, 0.f};
                    c = __builtin_amdgcn_mfma_f32_16x16x32_bf16(af0, bfrA[0][nt], c, 0, 0, 0);
                    c = __builtin_amdgcn_mfma_f32_16x16x32_bf16(af1, bfrA[1][nt], c, 0, 0, 0);
                    int col = nt * 16 + ln;
#pragma unroll
                    for (int r = 0; r < 4; r++) {
                        int row = row0 + rt * 16 + quad * 4 + r;
                        if (row < NNODES) {
                            size_t o = (size_t)row * DD + col;
                            if (wv == 0) A[o] = fbits(c[r] + bias[nt]);
                            else         Ed[o] = fbits(__expf(-(c[r] + bias[nt])));
                        }
                    }
                }
            }
        } else {
            const int rtb = (wv - 2) * 2;
#pragma unroll
            for (int rr = 0; rr < 2; rr++) {
                int rt = rtb + rr;
                int m = rt * 16 + ln;
                bf16x8 af0 = *(const bf16x8*)&xt[m * 72 + quad * 8];
                bf16x8 af1 = *(const bf16x8*)&xt[m * 72 + 32 + quad * 8];
#pragma unroll
                for (int nt = 0; nt < 4; nt++) {
                    f32x4 c2 = {0.f, 0.f, 0.f, 0.f};
                    f32x4 c3 = {0.f, 0.f, 0.f, 0.f};
                    c2 = __builtin_amdgcn_mfma_f32_16x16x32_bf16(af0, bfrA[0][nt], c2, 0, 0, 0);
                    c2 = __builtin_amdgcn_mfma_f32_16x16x32_bf16(af1, bfrA[1][nt], c2, 0, 0, 0);
                    c3 = __builtin_amdgcn_mfma_f32_16x16x32_bf16(af0, bfrB[0][nt], c3, 0, 0, 0);
                    c3 = __builtin_amdgcn_mfma_f32_16x16x32_bf16(af1, bfrB[1][nt], c3, 0, 0, 0);
                    int col = nt * 16 + ln;
#pragma unroll
                    for (int r = 0; r < 4; r++) {
                        int row = row0 + rt * 16 + quad * 4 + r;
                        if (row < NNODES)
                            Tw[(size_t)row * DD + col] =
                                pack2(c2[r], __expf(-c3[r]));
                    }
                }
            }
        }
    };

    // Pipelined tile loop (double-buffered x in the reclaimed weight LDS).
    stage_store(lsd, tid, xa, xb);
    int tn = t + GMM;
    if (tn < NGB)
        stage_load<MODE>(tn, tid, bfflag, u, v, A, abs_s, xa, xb);
    __syncthreads();
    int buf = 0;
    while (true) {
        compute(lsd + buf * 4608, t * DD);
        if (tn >= NGB) break;
        t = tn;
        tn += GMM;
        stage_store(lsd + (buf ^ 1) * 4608, tid, xa, xb);
        if (tn < NGB)
            stage_load<MODE>(tn, tid, bfflag, u, v, A, abs_s, xa, xb);
        __syncthreads();
        buf ^= 1;
    }
}

// ---- MFMA final: out = relu(ab*A + ab' + x_in@R); wave w = rowtile w.
// ab computed in-block from red2/gamma2/beta2 (fused k_stats).
__global__ __launch_bounds__(256) void k_final_mfma(
    const unsigned short* __restrict__ A, const float* __restrict__ red,
    const void* __restrict__ gm, const void* __restrict__ bt,
    const void* __restrict__ u, const void* __restrict__ v,
    const void* __restrict__ R, const int* __restrict__ flag,
    void* __restrict__ out)
{
    __shared__ __align__(16) unsigned short Wls[DD][72];
    __shared__ __align__(16) unsigned short xls[DD][72];
    __shared__ __align__(16) float abf[128];
    const int bfflag = flag[0];
    const int tid = threadIdx.x;
    if (tid < 64) {
        float mean = red[tid] * (1.f / NNODES);
        float var = red[64 + tid] * (1.f / NNODES) - mean * mean;
        float a = ldf(gm, tid, bfflag) * rsqrtf(var + 1e-3f);
        abf[tid] = a;
        abf[64 + tid] = ldf(bt, tid, bfflag) - mean * a;
    }
    if (bfflag) {
        for (int i = tid; i < 512; i += 256) {
            int e0 = i * 8;
            *(uint4*)&Wls[e0 >> 6][e0 & 63] = ((const uint4*)R)[i];
        }
    } else {
        for (int i = tid; i < 1024; i += 256) {
            int e0 = i * 4;
            float4 f = ((const float4*)R)[i];
            *(uint2*)&Wls[e0 >> 6][e0 & 63] =
                make_uint2(pack2(f.x, f.y), pack2(f.z, f.w));
        }
    }
    uint4 w0, w1;
    stage_load<0>(blockIdx.x, tid, bfflag, u, v, nullptr, nullptr, w0, w1);
    stage_store(&xls[0][0], tid, w0, w1);
    __syncthreads();

    const int row0 = blockIdx.x * DD;
    const int wv = tid >> 6, lane = tid & 63;
    const int quad = lane >> 4, ln = lane & 15;
    bf16x8 bfr[2][4];
#pragma unroll
    for (int ks = 0; ks < 2; ks++)
#pragma unroll
        for (int nt = 0; nt < 4; nt++)
#pragma unroll
            for (int j = 0; j < 8; j++)
                bfr[ks][nt][j] = (short)Wls[ks * 32 + quad * 8 + j][nt * 16 + ln];
    float av[4], bv[4];
#pragma unroll
    for (int nt = 0; nt < 4; nt++) {
        av[nt] = abf[nt * 16 + ln];
        bv[nt] = abf[64 + nt * 16 + ln];
    }
    const int rt = wv;
    int m = rt * 16 + ln;
    bf16x8 af0 = *(const bf16x8*)&xls[m][quad * 8];
    bf16x8 af1 = *(const bf16x8*)&xls[m][32 + quad * 8];
#pragma unroll
    for (int nt = 0; nt < 4; nt++) {
        f32x4 c = {0.f, 0.f, 0.f, 0.f};
        c = __builtin_amdgcn_mfma_f32_16x16x32_bf16(af0, bfr[0][nt], c, 0, 0, 0);
        c = __builtin_amdgcn_mfma_f32_16x16x32_bf16(af1, bfr[1][nt], c, 0, 0, 0);
        int col = nt * 16 + ln;
#pragma unroll
        for (int r = 0; r < 4; r++) {
            int row = row0 + rt * 16 + quad * 4 + r;
            if (row < NNODES) {
                size_t o = (size_t)row * DD + col;
                float vv = av[nt] * us2f(A[o]) + bv[nt] + c[r];
                vv = vv > 0.f ? vv : 0.f;
                if (bfflag) ((unsigned short*)out)[o] = fbits(vv);
                else        ((float*)out)[o] = vv;
            }
        }
    }
}

// ---- Gather-accumulate v2: grid-stride waves over dst nodes, batched loads,
// fused column-sum/sumsq reduction (k_reduce removed).
// sigma(gd+gs) = 1/(1 + e^-gd * e^-gs) = rcp(1 + Ed*Es) — no exp in the loop.
// srcidx holds BYTE offsets (src*256). Per-edge addr = SGPR add only.
// 16-deep branch-free clamped load batch: all gathers in flight before compute.
__global__ __launch_bounds__(256) void k_accum(
    const int* __restrict__ rowptr, const int* __restrict__ srcidx,
    const unsigned* __restrict__ T, const bf16* __restrict__ Ed,
    unsigned short* __restrict__ A, float* __restrict__ red)
{
    __shared__ float s1[256], s2[256];
    const int c = threadIdx.x & 63;
    const char* Tb = (const char*)T + (c << 2);
    float rsum = 0.f, rsq = 0.f;

    int d = blockIdx.x * 4 + (threadIdx.x >> 6);  // < DSTR <= NNODES
    int r0 = rowptr[d], r1 = rowptr[d + 1];
    size_t o = (size_t)d * DD + c;
    float ed = b2f(Ed[o]);
    float sum = us2f(A[o]);

    while (true) {
        // Prefetch next node's header while current edges process.
        int dn = d + DSTR;
        int r0n = 0, r1n = 0;
        size_t on = 0;
        float edn = 0.f, sumn = 0.f;
        if (dn < NNODES) {
            r0n = rowptr[dn];
            r1n = rowptr[dn + 1];
            on = (size_t)dn * DD + c;
            edn = b2f(Ed[on]);
            sumn = us2f(A[on]);
        }

        int i = r0;
        while (i < r1) {
            int nb = r1 - i;
            nb = nb > 16 ? 16 : nb;
            int last = r1 - 1;
            unsigned tv[16];
#pragma unroll
            for (int j = 0; j < 16; j++) {
                int idx = i + j;
                idx = idx < last ? idx : last;  // clamp: branch-free, safe
                tv[j] = *(const unsigned*)(Tb + (unsigned)srcidx[idx]);
            }
#pragma unroll
            for (int j = 0; j < 16; j++)
                if (j < nb)
                    sum += lo_bf16(tv[j]) *
                        __builtin_amdgcn_rcpf(1.f + ed * hi_bf16(tv[j]));
            i += nb;
        }
        A[o] = fbits(sum);
        rsum += sum;
        rsq += sum * sum;
        if (dn >= NNODES) break;
        d = dn; r0 = r0n; r1 = r1n; o = on; ed = edn; sum = sumn;
    }

    // fused k_reduce: block partial -> 2 atomics per column
    s1[threadIdx.x] = rsum;
    s2[threadIdx.x] = rsq;
    __syncthreads();
    if (threadIdx.x < 64) {
        float a = s1[c] + s1[64 + c] + s1[128 + c] + s1[192 + c];
        float b = s2[c] + s2[64 + c] + s2[128 + c] + s2[192 + c];
        unsafeAtomicAdd(&red[c], a);
        unsafeAtomicAdd(&red[64 + c], b);
    }
}

extern "C" void kernel_launch(void* const* d_in, const int* in_sizes, int n_in,
                              void* d_out, int out_size, void* d_ws, size_t ws_size,
                              hipStream_t stream)
{
    const void* u   = d_in[0];
    const void* v   = d_in[1];
    const int* es   = (const int*)d_in[2];
    const int* ee   = (const int*)d_in[3];
    const void* Ui1 = d_in[4];
    const void* Uj1 = d_in[5];
    const void* Vi1 = d_in[6];
    const void* Vj1 = d_in[7];
    const void* bu1 = d_in[8];
    const void* bv1 = d_in[9];
    const void* Ui2 = d_in[10];
    const void* Uj2 = d_in[11];
    const void* Vi2 = d_in[12];
    const void* Vj2 = d_in[13];
    const void* bu2 = d_in[14];
    const void* bv2 = d_in[15];
    const void* R   = d_in[16];
    const void* g1  = d_in[17];
    const void* be1 = d_in[18];
    const void* g2  = d_in[19];
    const void* be2 = d_in[20];
    const int E = in_sizes[2];

    // Workspace (~56.8 MB; proven layout — offsets unchanged, A bf16).
    // ebuf aliases T (CSR build fully precedes k_mm4<0>'s T writes).
    // Ed table lives in d_out until k_final overwrites it.
    char* ws = (char*)d_ws;
    unsigned short* A = (unsigned short*)(ws);      // 12.8 MB bf16 accumulator
    unsigned* T    = (unsigned*)(ws + 25600000);    // 25.6 MB (Ui | exp(-Vj)<<16)
    unsigned* ebuf = (unsigned*)(ws + 25600000);    // 4 MB, aliases T
    int* srcidx    = (int*)(ws + 51200000);         // 4 MB
    int* rowptr    = (int*)(ws + 56000000);         // 400,004 B
    float* red     = (float*)(ws + 56802176);       // red1/red2 (1 KB)
    int* flag      = (int*)(ws + 56804224);
    int* btot      = (int*)(ws + 56804352);         // 256 ints
    int* bbase     = (int*)(ws + 56805376);         // 256 ints (ends 56806400)
    int* bcursor   = (int*)(ws + 56806400);         // 256 ints
    float* red1 = red, *red2 = red + 128;
    bf16* Ed = (bf16*)d_out;

    // ---- dtype sniff + bucketed CSR build ----
    k_sniff<<<1, 256, 0, stream>>>((const unsigned short*)u, flag, red, btot);
    k_bhist<<<400, 256, 0, stream>>>(ee, btot, E);
    k_bscan<<<1, 256, 0, stream>>>(btot, bbase, bcursor);
    k_bscatter<<<(E + ESB - 1) / ESB, 256, 0, stream>>>(es, ee, bcursor, ebuf, E);
    k_group<<<NBUK, 256, 0, stream>>>(bbase, ebuf, rowptr, srcidx);

    // ---- stage 1 ----
    k_mm4_mfma<0><<<GMM, 256, 0, stream>>>(u, v, nullptr, nullptr, nullptr,
                                           Uj1, Vi1, Ui1, Vj1, bu1, bv1, flag,
                                           A, (unsigned short*)Ed, T);
    k_accum<<<ACB, 256, 0, stream>>>(rowptr, srcidx, T, Ed, A, red1);

    // ---- stage 2 (BN1+relu fused into staging; stats fused into k_mm4) ----
    k_mm4_mfma<1><<<GMM, 256, 0, stream>>>(nullptr, nullptr, red1, g1, be1,
                                           Uj2, Vi2, Ui2, Vj2, bu2, bv2, flag,
                                           A, (unsigned short*)Ed, T);
    k_accum<<<ACB, 256, 0, stream>>>(rowptr, srcidx, T, Ed, A, red2);

    // ---- BN2 + residual (x_in@R via MFMA) + relu -> out ----
    k_final_mfma<<<NGB, 256, 0, stream>>>(A, red2, g2, be2, u, v, R, flag, d_out);
}